// Round 8
// baseline (248.944 us; speedup 1.0000x reference)
//
#include <hip/hip_runtime.h>

// GADBase guided anisotropic diffusion on MI355X — round 18 (resubmit; R7 was
// "MI355X container failed twice" — infra provisioning failure, kernel never
// ran. Deadlock re-audit clean: co-residency 256/256, publish/consume
// causality chain identical to verified R13/R16/R17, batch-seam masks off,
// LDS parity consistent, __all over wave-uniform predicates).
// R17 (PASSED, 231us total / 167us persist): linear-correction split covered
// the detect chain; residual 1.5us/round = all-wave stall with 2 correlated
// blocks sharing each CU (VALUBusy 42%).
// R18: one block per CU + register-resident interior.
//  - NB 256, tile 64x128, TPB 256 -> 1 block/CU: full issue rate, half the
//    Y-skew depth, half the publish traffic.
//  - interior lives in cur[8] float4 registers (in-place rolling stencil);
//    LDS holds ONLY the per-cyL-group boundary rows: bnd[2][8][2][128] (16KB,
//    parity-alternated, one barrier per round).
//  - 8x8 ratio cell = 2 lanes (g, g^1): csum reduce is a single shfl_xor.
// Inter-block protocol unchanged from R17 (verified): tagged uncached
// publishes, parity-2 slots, poll-issue -> base compute -> resolve ->
// linear corrections; col lines are now 64 u64 (8 rows/thread on the edge).

#define BB 2
#define HH 1024
#define WW 1024
#define NPIX (HH * WW)
#define CVN (1023 * 1024)
#define SHW (128 * 128)
#define LL 0.24f
#define KK2 (0.03f * 0.03f)
#define EPSF 1e-8f
#define DEPSF 0.1f
#define NPRE 64
#define NB 256            // 1 block/CU on 256 CUs — co-resident
#define TPB 256

typedef unsigned long long u64;
typedef unsigned int uint4v __attribute__((ext_vector_type(4)));
#define ROWPAR ((size_t)NB * 2 * 128)   // u64s per parity plane (row buffers)
#define COLPAR ((size_t)NB * 2 * 64)

// uncached (MALL-coherent) 16B store / load
__device__ inline void ust4(void* p, uint4v q) {
    asm volatile("global_store_dwordx4 %0, %1, off sc0 sc1" :: "v"(p), "v"(q) : "memory");
}
__device__ inline uint4v uld4(const void* p) {
    uint4v r;
    asm volatile("global_load_dwordx4 %0, %1, off sc0 sc1" : "=v"(r) : "v"(p) : "memory");
    return r;
}
__device__ inline void vwait() { asm volatile("s_waitcnt vmcnt(0)" ::: "memory"); }

__device__ inline void pub2(u64* p, float v0, float v1, unsigned s) {
    uint4v q;
    q.x = __float_as_uint(v0); q.y = s;
    q.z = __float_as_uint(v1); q.w = s;
    ust4(p, q);
}
__device__ inline bool tags_ok(uint4v a, uint4v b, unsigned s) {
    return a.y == s && a.w == s && b.y == s && b.w == s;
}
__device__ inline float4 vals_of(uint4v a, uint4v b) {
    return make_float4(__uint_as_float(a.x), __uint_as_float(a.z),
                       __uint_as_float(b.x), __uint_as_float(b.z));
}

__device__ inline float gfun(float d) { return 1.0f / (1.0f + (d * d) / KK2); }

// raw barrier: LDS visibility only. Publish stores (vmcnt) NOT drained.
#define BAR() do { asm volatile("s_waitcnt lgkmcnt(0)" ::: "memory"); \
                   __builtin_amdgcn_s_barrier();                      \
                   __builtin_amdgcn_sched_barrier(0); } while (0)

__launch_bounds__(TPB, 1)
__global__ void persist_kernel(const float* __restrict__ guide, const float* __restrict__ yb,
                               const float* __restrict__ src, const float* __restrict__ mask,
                               float* __restrict__ out, float* __restrict__ out_cv,
                               float* __restrict__ out_ch,
                               u64* __restrict__ bufRow, u64* __restrict__ bufCol) {
    __shared__ float bnd[2][8][2][128];   // [parity][cyL][top/bot][col] 16KB
    __shared__ float sm[4];
    int blk = blockIdx.x;
    int b = blk >> 7;
    int r = blk & 127;
    int tileY = r >> 3;          // 0..15
    int tileX = r & 7;           // 0..7
    int tid = threadIdx.x;
    int cyL = tid >> 5;          // 0..7 (8 rows each)
    int g = tid & 31;            // 0..31
    int wv = tid >> 6;           // wave 0..3
    int l0 = tid & 63;           // lane within wave
    int lx0 = g * 4;
    int ly0 = cyL * 8;
    int gx = tileX * 128 + lx0;
    int gy = tileY * 64 + ly0;

    // ---- phase 0: shift (redundant per-block, deterministic order) ----
    float mmin = 1e30f;
    const float4* s4 = (const float4*)src;
    for (int i = tid; i < (BB * SHW) / 4; i += TPB) {
        float4 v = s4[i];
        mmin = fminf(mmin, fminf(fminf(v.x, v.y), fminf(v.z, v.w)));
    }
    for (int off = 32; off > 0; off >>= 1) mmin = fminf(mmin, __shfl_down(mmin, off));
    if ((tid & 63) == 0) sm[tid >> 6] = mmin;
    __syncthreads();
    float mm = fminf(fminf(sm[0], sm[1]), fminf(sm[2], sm[3]));
    float shift = (mm <= DEPSF) ? DEPSF : 0.0f;

    // ---- phase 1: conductances from guide/yb (shift cancels in diffs) ----
    int ry[10];
#pragma unroll
    for (int j = 0; j < 10; ++j) {
        int y = gy - 1 + j;
        ry[j] = y < 0 ? 0 : (y > 1023 ? 1023 : y);
    }
    int cxl = (gx > 0) ? gx - 1 : 0;
    int cxr = (gx + 4 < 1024) ? gx + 4 : 1023;
    float4 z4 = make_float4(0.f, 0.f, 0.f, 0.f);
    float4 vd[9] = {z4, z4, z4, z4, z4, z4, z4, z4, z4};
    float4 hd[8] = {z4, z4, z4, z4, z4, z4, z4, z4};
    float hmd[8] = {0.f, 0.f, 0.f, 0.f, 0.f, 0.f, 0.f, 0.f};
    float4 imv[8], r0v = z4, r9v = z4;
    float slv[8], srv[8];
#pragma unroll
    for (int c = 0; c < 4; ++c) {
        const float* F = (c < 3) ? guide + ((size_t)b * 3 + c) * NPIX
                                 : yb + (size_t)b * NPIX;
        float4 rr[10];
#pragma unroll
        for (int j = 0; j < 10; ++j)
            rr[j] = *(const float4*)(F + (size_t)ry[j] * WW + gx);
#pragma unroll
        for (int j = 0; j < 9; ++j) {
            vd[j].x += fabsf(rr[j + 1].x - rr[j].x);
            vd[j].y += fabsf(rr[j + 1].y - rr[j].y);
            vd[j].z += fabsf(rr[j + 1].z - rr[j].z);
            vd[j].w += fabsf(rr[j + 1].w - rr[j].w);
        }
#pragma unroll
        for (int k = 0; k < 8; ++k) {
            float4 R = rr[k + 1];
            float sr = F[(size_t)ry[k + 1] * WW + cxr];
            float sl = F[(size_t)ry[k + 1] * WW + cxl];
            hd[k].x += fabsf(R.y - R.x);
            hd[k].y += fabsf(R.z - R.y);
            hd[k].z += fabsf(R.w - R.z);
            hd[k].w += fabsf(sr - R.w);
            hmd[k] += fabsf(R.x - sl);
            if (c == 3) { imv[k] = R; slv[k] = sl; srv[k] = sr; }
        }
        if (c == 3) { r0v = rr[0]; r9v = rr[9]; }
    }
    float4 cvR[9], chR[8];
    float hmR[8];
#pragma unroll
    for (int j = 0; j < 9; ++j) {
        int y = gy - 1 + j;
        if (y < 0 || y > 1022) {
            cvR[j] = z4;
        } else {
            cvR[j] = make_float4(gfun(vd[j].x * 0.25f), gfun(vd[j].y * 0.25f),
                                 gfun(vd[j].z * 0.25f), gfun(vd[j].w * 0.25f));
        }
    }
#pragma unroll
    for (int k = 0; k < 8; ++k) {
        chR[k] = make_float4(gfun(hd[k].x * 0.25f), gfun(hd[k].y * 0.25f),
                             gfun(hd[k].z * 0.25f), gfun(hd[k].w * 0.25f));
        if (gx + 3 == 1023) chR[k].w = 0.f;
        hmR[k] = (gx > 0) ? gfun(hmd[k] * 0.25f) : 0.f;
    }
    // cv/ch output slices for this tile
#pragma unroll
    for (int j = 1; j < 9; ++j) {
        int y = gy + j - 1;
        if (y <= 1022)
            *(float4*)(out_cv + (size_t)b * CVN + (size_t)y * WW + gx) = cvR[j];
    }
#pragma unroll
    for (int k = 0; k < 8; ++k) {
        float* base = out_ch + (size_t)b * CVN + (size_t)(gy + k) * 1023;
        base[gx + 0] = chR[k].x;
        base[gx + 1] = chR[k].y;
        base[gx + 2] = chR[k].z;
        if (gx + 3 < 1023) base[gx + 3] = chR[k].w;
    }

    // 8x8 cell: rows ly0..ly0+7 (this cyL), cols = pair (g, g^1)
    int sidx = b * SHW + (tileY * 8 + cyL) * 128 + tileX * 16 + (g >> 1);
    float sval = src[sidx] + shift;
    bool masked = mask[sidx] < 0.5f;

    bool upAct = (cyL == 0 && tileY > 0);
    bool dnAct = (cyL == 7 && tileY < 15);
    bool lAct  = (g == 0  && tileX > 0);
    bool rAct  = (g == 31 && tileX < 7);
    bool pubTop = (wv == 0 && tileY > 0);
    bool pubBot = (wv == 3 && tileY < 15);

    // interior state in registers; init img0 = yb + shift
    float4 cur[8];
#pragma unroll
    for (int k = 0; k < 8; ++k) {
        float4 v = imv[k];
        v.x += shift; v.y += shift; v.z += shift; v.w += shift;
        cur[k] = v;
    }
    float4 hUp = z4, hDn = z4;
    float xlR[8] = {0.f, 0.f, 0.f, 0.f, 0.f, 0.f, 0.f, 0.f};
    float xrR[8] = {0.f, 0.f, 0.f, 0.f, 0.f, 0.f, 0.f, 0.f};
    if (upAct) { hUp = r0v; hUp.x += shift; hUp.y += shift; hUp.z += shift; hUp.w += shift; }
    if (dnAct) { hDn = r9v; hDn.x += shift; hDn.y += shift; hDn.z += shift; hDn.w += shift; }
    if (lAct) {
#pragma unroll
        for (int k = 0; k < 8; ++k) xlR[k] = slv[k] + shift;
    }
    if (rAct) {
#pragma unroll
        for (int k = 0; k < 8; ++k) xrR[k] = srv[k] + shift;
    }
    // seed boundary LDS slot 0 with state-0 top/bot rows
    *(float4*)&bnd[0][cyL][0][lx0] = cur[0];
    *(float4*)&bnd[0][cyL][1][lx0] = cur[7];
    __syncthreads();

    for (int t = 0; t < NPRE; ++t) {
        int par = t & 1;
        // ---- 1: issue poll loads for state-t halos (tag=t, parity=t&1) ----
        unsigned sP = (unsigned)t;
        size_t rOffP = par ? ROWPAR : 0;
        size_t cOffP = par ? COLPAR : 0;
        const u64* pUp = upAct ? &bufRow[rOffP + (((size_t)blk - 8) * 2 + 1) * 128 + lx0] : nullptr;
        const u64* pDn = dnAct ? &bufRow[rOffP + (((size_t)blk + 8) * 2 + 0) * 128 + lx0] : nullptr;
        const u64* pL  = lAct  ? &bufCol[cOffP + (((size_t)blk - 1) * 2 + 1) * 64 + ly0] : nullptr;
        const u64* pR  = rAct  ? &bufCol[cOffP + (((size_t)blk + 1) * 2 + 0) * 64 + ly0] : nullptr;
        uint4v uA, uB, dA, dB, lA, lB, lC, lD, rA, rB, rC, rD;
        bool pollRound = (t > 0);    // t==0 halos live in registers from init
        if (pollRound) {
            if (upAct) { uA = uld4(pUp); uB = uld4(pUp + 2); }
            if (dnAct) { dA = uld4(pDn); dB = uld4(pDn + 2); }
            if (lAct)  { lA = uld4(pL);  lB = uld4(pL + 2); lC = uld4(pL + 4); lD = uld4(pL + 6); }
            if (rAct)  { rA = uld4(pR);  rB = uld4(pR + 2); rC = uld4(pR + 4); rD = uld4(pR + 6); }
        }

        // ---- 2: intra-tile boundary rows of state t from LDS slot par ----
        float4 ldsUp = z4, ldsDn = z4;
        if (cyL > 0) ldsUp = *(float4*)&bnd[par][cyL - 1][1][lx0];
        if (cyL < 7) ldsDn = *(float4*)&bnd[par][cyL + 1][0][lx0];

        // ---- 3: BASE stencil in registers (halo terms = 0), in-place ----
        float4 pu = (cyL == 0) ? z4 : ldsUp;
        float4 pc = cur[0];
        float csum = 0.f;
#pragma unroll
        for (int k = 0; k < 8; ++k) {
            float4 dn = (k == 7) ? ((cyL == 7) ? z4 : ldsDn) : cur[k + 1];
            float4 cu = cvR[k], cd = cvR[k + 1], h4 = chR[k];
            float xs = __shfl_up(pc.w, 1);
            float xt = __shfl_down(pc.x, 1);
            float xl = (g == 0)  ? 0.f : xs;
            float xr = (g == 31) ? 0.f : xt;
            float hm = hmR[k];
            float4 a;
            a.x = pc.x + LL * (cd.x * (dn.x - pc.x) - cu.x * (pc.x - pu.x)
                             + h4.x * (pc.y - pc.x) - hm   * (pc.x - xl));
            a.y = pc.y + LL * (cd.y * (dn.y - pc.y) - cu.y * (pc.y - pu.y)
                             + h4.y * (pc.z - pc.y) - h4.x * (pc.y - pc.x));
            a.z = pc.z + LL * (cd.z * (dn.z - pc.z) - cu.z * (pc.z - pu.z)
                             + h4.z * (pc.w - pc.z) - h4.y * (pc.z - pc.y));
            a.w = pc.w + LL * (cd.w * (dn.w - pc.w) - cu.w * (pc.w - pu.w)
                             + h4.w * (xr   - pc.w) - h4.z * (pc.w - pc.z));
            csum += a.x + a.y + a.z + a.w;
            cur[k] = a;
            pu = pc; pc = dn;
        }

        // ---- 4: resolve halos (loads had the whole base compute to land) ----
        if (pollRound) {
            vwait();
            bool needU = upAct, needD = dnAct, needL = lAct, needR = rAct;
            for (;;) {
                if (needU && tags_ok(uA, uB, sP)) { hUp = vals_of(uA, uB); needU = false; }
                if (needD && tags_ok(dA, dB, sP)) { hDn = vals_of(dA, dB); needD = false; }
                if (needL && tags_ok(lA, lB, sP) && tags_ok(lC, lD, sP)) {
                    float4 c1 = vals_of(lA, lB), c2 = vals_of(lC, lD);
                    xlR[0] = c1.x; xlR[1] = c1.y; xlR[2] = c1.z; xlR[3] = c1.w;
                    xlR[4] = c2.x; xlR[5] = c2.y; xlR[6] = c2.z; xlR[7] = c2.w;
                    needL = false;
                }
                if (needR && tags_ok(rA, rB, sP) && tags_ok(rC, rD, sP)) {
                    float4 c1 = vals_of(rA, rB), c2 = vals_of(rC, rD);
                    xrR[0] = c1.x; xrR[1] = c1.y; xrR[2] = c1.z; xrR[3] = c1.w;
                    xrR[4] = c2.x; xrR[5] = c2.y; xrR[6] = c2.z; xrR[7] = c2.w;
                    needR = false;
                }
                if (__all(!(needU || needD || needL || needR))) break;
                __builtin_amdgcn_s_sleep(1);
                if (needU) { uA = uld4(pUp); uB = uld4(pUp + 2); }
                if (needD) { dA = uld4(pDn); dB = uld4(pDn + 2); }
                if (needL) { lA = uld4(pL);  lB = uld4(pL + 2); lC = uld4(pL + 4); lD = uld4(pL + 6); }
                if (needR) { rA = uld4(pR);  rB = uld4(pR + 2); rC = uld4(pR + 4); rD = uld4(pR + 6); }
                vwait();
            }
        }

        // ---- 5: linear corrections (zero-conductance borders self-mask) ----
        float cadd = 0.f;
        if (cyL == 0) {
            float4 cu = cvR[0];
            float c0 = LL * cu.x * hUp.x, c1 = LL * cu.y * hUp.y;
            float c2 = LL * cu.z * hUp.z, c3 = LL * cu.w * hUp.w;
            cur[0].x += c0; cur[0].y += c1; cur[0].z += c2; cur[0].w += c3;
            cadd += c0 + c1 + c2 + c3;
        }
        if (cyL == 7) {
            float4 cd = cvR[8];
            float c0 = LL * cd.x * hDn.x, c1 = LL * cd.y * hDn.y;
            float c2 = LL * cd.z * hDn.z, c3 = LL * cd.w * hDn.w;
            cur[7].x += c0; cur[7].y += c1; cur[7].z += c2; cur[7].w += c3;
            cadd += c0 + c1 + c2 + c3;
        }
        if (g == 0) {
#pragma unroll
            for (int k = 0; k < 8; ++k) {
                float c = LL * hmR[k] * xlR[k];
                cur[k].x += c; cadd += c;
            }
        }
        if (g == 31) {
#pragma unroll
            for (int k = 0; k < 8; ++k) {
                float c = LL * chR[k].w * xrR[k];
                cur[k].w += c; cadd += c;
            }
        }
        csum += cadd;
        csum += __shfl_xor(csum, 1);   // cell = 8 rows x 8 cols = lanes {g, g^1}
        float ratio = masked ? 1.0f : sval / (csum * (1.0f / 64.0f) + EPSF);

        if (t == NPRE - 1) {
            float* ob = out + (size_t)b * NPIX;
#pragma unroll
            for (int k = 0; k < 8; ++k) {
                float4 v = cur[k];
                v.x = v.x * ratio - shift; v.y = v.y * ratio - shift;
                v.z = v.z * ratio - shift; v.w = v.w * ratio - shift;
                *(float4*)(ob + (size_t)(gy + k) * WW + gx) = v;
            }
            break;
        }
#pragma unroll
        for (int k = 0; k < 8; ++k) {
            cur[k].x *= ratio; cur[k].y *= ratio; cur[k].z *= ratio; cur[k].w *= ratio;
        }

        // ---- 6: publish edges tagged s2 = t+1 ----
        unsigned s2 = (unsigned)(t + 1);
        size_t rOff2 = (s2 & 1) ? ROWPAR : 0;
        size_t cOff2 = (s2 & 1) ? COLPAR : 0;
        if (pubTop) {   // wave 0: top row lives in cur[0] of lanes 0..31 (cyL0)
            float a = __shfl(cur[0].x, l0 >> 1), bq = __shfl(cur[0].y, l0 >> 1);
            float c = __shfl(cur[0].z, l0 >> 1), d = __shfl(cur[0].w, l0 >> 1);
            float v0 = (l0 & 1) ? c : a, v1 = (l0 & 1) ? d : bq;
            uint4v q; q.x = __float_as_uint(v0); q.y = s2;
            q.z = __float_as_uint(v1); q.w = s2;
            ust4(&bufRow[rOff2 + ((size_t)blk * 2 + 0) * 128 + 2 * l0], q);
        }
        if (pubBot) {   // wave 3: bottom row in cur[7] of local lanes 32..63 (cyL7)
            int sl = 32 + (l0 >> 1);
            float a = __shfl(cur[7].x, sl), bq = __shfl(cur[7].y, sl);
            float c = __shfl(cur[7].z, sl), d = __shfl(cur[7].w, sl);
            float v0 = (l0 & 1) ? c : a, v1 = (l0 & 1) ? d : bq;
            uint4v q; q.x = __float_as_uint(v0); q.y = s2;
            q.z = __float_as_uint(v1); q.w = s2;
            ust4(&bufRow[rOff2 + ((size_t)blk * 2 + 1) * 128 + 2 * l0], q);
        }
        if (lAct) {     // 8 rows per edge thread = 4 x 16B
            u64* p = &bufCol[cOff2 + ((size_t)blk * 2 + 0) * 64 + ly0];
            pub2(p,     cur[0].x, cur[1].x, s2);
            pub2(p + 2, cur[2].x, cur[3].x, s2);
            pub2(p + 4, cur[4].x, cur[5].x, s2);
            pub2(p + 6, cur[6].x, cur[7].x, s2);
        }
        if (rAct) {
            u64* p = &bufCol[cOff2 + ((size_t)blk * 2 + 1) * 64 + ly0];
            pub2(p,     cur[0].w, cur[1].w, s2);
            pub2(p + 2, cur[2].w, cur[3].w, s2);
            pub2(p + 4, cur[4].w, cur[5].w, s2);
            pub2(p + 6, cur[6].w, cur[7].w, s2);
        }

        // ---- 7: boundary rows of state t+1 into LDS slot par^1; barrier ----
        *(float4*)&bnd[par ^ 1][cyL][0][lx0] = cur[0];
        *(float4*)&bnd[par ^ 1][cyL][1][lx0] = cur[7];
        BAR();   // publish stores cross in flight; LDS visible
    }
}

extern "C" void kernel_launch(void* const* d_in, const int* in_sizes, int n_in,
                              void* d_out, int out_size, void* d_ws, size_t ws_size,
                              hipStream_t stream) {
    const float* guide = (const float*)d_in[0];   // [2,3,1024,1024]
    const float* yb    = (const float*)d_in[1];   // [2,1,1024,1024]
    const float* src   = (const float*)d_in[2];   // [2,1,128,128]
    const float* mask  = (const float*)d_in[3];   // [2,1,128,128]

    float* out    = (float*)d_out;                       // y_pred [2,1,1024,1024]
    float* out_cv = out + (size_t)BB * NPIX;             // cv [2,1,1023,1024]
    float* out_ch = out_cv + (size_t)BB * CVN;           // ch [2,1,1024,1023]

    // ws: halo exchange buffers only. 0xAA poison can't match tags in [1,64).
    u64* bufRow = (u64*)d_ws;                            // 2 par x 256 x 2 x 128
    u64* bufCol = bufRow + 2 * ROWPAR;                   // 2 par x 256 x 2 x 64

    persist_kernel<<<NB, TPB, 0, stream>>>(guide, yb, src, mask, out, out_cv,
                                           out_ch, bufRow, bufCol);
}

// Round 10
// 219.556 us; speedup vs baseline: 1.1338x; 1.1338x over previous
//
#include <hip/hip_runtime.h>

// GADBase guided anisotropic diffusion on MI355X — round 19 (resubmit; R9 was
// a broker GPUAcquisitionTimeout, kernel never ran).
// R18 (PASSED, 249us total / 185us persist) REGRESSED vs R17 (167us):
// 1 block x 4 waves/CU = 1 wave/SIMD -> no latency hiding (VALUBusy fell
// 42.8 -> 33.4). But R18 proved the register-interior + boundary-only-LDS
// structure: bank conflicts 8.4M -> 0, FETCH 65->53GB, WRITE 115->83GB.
// R19 recombines the proven halves: TPB 512 (8 waves = 2/SIMD, 1 block/CU),
// tile 64x128, each thread 4 rows (cur[4], 16 cyL groups):
//  - restores R17's 2-waves/SIMD latency hiding regime;
//  - keeps zero-conflict bnd[2][16][2][128] (32KB) boundary exchange;
//  - keeps halved Y-interface count (15 seams vs R17's 31) and publish volume;
//  - one barrier syncs 64 rows/round.
// Inter-block protocol/poll/cell-reduce byte-identical to verified R17/R18
// (tags, parity-2, uncached publishes, poll-issue -> base compute -> resolve
// -> linear corrections; cell lanes {tid,tid^1,tid^32,tid^33}).

#define BB 2
#define HH 1024
#define WW 1024
#define NPIX (HH * WW)
#define CVN (1023 * 1024)
#define SHW (128 * 128)
#define LL 0.24f
#define KK2 (0.03f * 0.03f)
#define EPSF 1e-8f
#define DEPSF 0.1f
#define NPRE 64
#define NB 256            // 1 block/CU on 256 CUs — co-resident
#define TPB 512           // 8 waves = 2 waves/SIMD

typedef unsigned long long u64;
typedef unsigned int uint4v __attribute__((ext_vector_type(4)));
#define ROWPAR ((size_t)NB * 2 * 128)   // u64s per parity plane (row buffers)
#define COLPAR ((size_t)NB * 2 * 64)

// uncached (MALL-coherent) 16B store / load
__device__ inline void ust4(void* p, uint4v q) {
    asm volatile("global_store_dwordx4 %0, %1, off sc0 sc1" :: "v"(p), "v"(q) : "memory");
}
__device__ inline uint4v uld4(const void* p) {
    uint4v r;
    asm volatile("global_load_dwordx4 %0, %1, off sc0 sc1" : "=v"(r) : "v"(p) : "memory");
    return r;
}
__device__ inline void vwait() { asm volatile("s_waitcnt vmcnt(0)" ::: "memory"); }

__device__ inline void pub2(u64* p, float v0, float v1, unsigned s) {
    uint4v q;
    q.x = __float_as_uint(v0); q.y = s;
    q.z = __float_as_uint(v1); q.w = s;
    ust4(p, q);
}
__device__ inline bool tags_ok(uint4v a, uint4v b, unsigned s) {
    return a.y == s && a.w == s && b.y == s && b.w == s;
}
__device__ inline float4 vals_of(uint4v a, uint4v b) {
    return make_float4(__uint_as_float(a.x), __uint_as_float(a.z),
                       __uint_as_float(b.x), __uint_as_float(b.z));
}

__device__ inline float gfun(float d) { return 1.0f / (1.0f + (d * d) / KK2); }

// raw barrier: LDS visibility only. Publish stores (vmcnt) NOT drained.
#define BAR() do { asm volatile("s_waitcnt lgkmcnt(0)" ::: "memory"); \
                   __builtin_amdgcn_s_barrier();                      \
                   __builtin_amdgcn_sched_barrier(0); } while (0)

__launch_bounds__(TPB, 2)
__global__ void persist_kernel(const float* __restrict__ guide, const float* __restrict__ yb,
                               const float* __restrict__ src, const float* __restrict__ mask,
                               float* __restrict__ out, float* __restrict__ out_cv,
                               float* __restrict__ out_ch,
                               u64* __restrict__ bufRow, u64* __restrict__ bufCol) {
    __shared__ float bnd[2][16][2][128];   // [parity][cyL][top/bot][col] 32KB
    __shared__ float sm[8];
    int blk = blockIdx.x;
    int b = blk >> 7;
    int r = blk & 127;
    int tileY = r >> 3;          // 0..15
    int tileX = r & 7;           // 0..7
    int tid = threadIdx.x;
    int cyL = tid >> 5;          // 0..15 (4 rows each)
    int g = tid & 31;            // 0..31
    int wv = tid >> 6;           // wave 0..7
    int l0 = tid & 63;           // lane within wave
    int lx0 = g * 4;
    int ly0 = cyL * 4;
    int gx = tileX * 128 + lx0;
    int gy = tileY * 64 + ly0;

    // ---- phase 0: shift (redundant per-block, deterministic order) ----
    float mmin = 1e30f;
    const float4* s4 = (const float4*)src;
    for (int i = tid; i < (BB * SHW) / 4; i += TPB) {
        float4 v = s4[i];
        mmin = fminf(mmin, fminf(fminf(v.x, v.y), fminf(v.z, v.w)));
    }
    for (int off = 32; off > 0; off >>= 1) mmin = fminf(mmin, __shfl_down(mmin, off));
    if ((tid & 63) == 0) sm[tid >> 6] = mmin;
    __syncthreads();
    float mm = fminf(fminf(fminf(sm[0], sm[1]), fminf(sm[2], sm[3])),
                     fminf(fminf(sm[4], sm[5]), fminf(sm[6], sm[7])));
    float shift = (mm <= DEPSF) ? DEPSF : 0.0f;

    // ---- phase 1: conductances from guide/yb (shift cancels in diffs) ----
    int ry[6];
#pragma unroll
    for (int j = 0; j < 6; ++j) {
        int y = gy - 1 + j;
        ry[j] = y < 0 ? 0 : (y > 1023 ? 1023 : y);
    }
    int cxl = (gx > 0) ? gx - 1 : 0;
    int cxr = (gx + 4 < 1024) ? gx + 4 : 1023;
    float4 z4 = make_float4(0.f, 0.f, 0.f, 0.f);
    float4 vd[5] = {z4, z4, z4, z4, z4};
    float4 hd[4] = {z4, z4, z4, z4};
    float hmd[4] = {0.f, 0.f, 0.f, 0.f};
    float4 imv[4], r0v = z4, r5v = z4;
    float slv[4], srv[4];
#pragma unroll
    for (int c = 0; c < 4; ++c) {
        const float* F = (c < 3) ? guide + ((size_t)b * 3 + c) * NPIX
                                 : yb + (size_t)b * NPIX;
        float4 rr[6];
#pragma unroll
        for (int j = 0; j < 6; ++j)
            rr[j] = *(const float4*)(F + (size_t)ry[j] * WW + gx);
#pragma unroll
        for (int j = 0; j < 5; ++j) {
            vd[j].x += fabsf(rr[j + 1].x - rr[j].x);
            vd[j].y += fabsf(rr[j + 1].y - rr[j].y);
            vd[j].z += fabsf(rr[j + 1].z - rr[j].z);
            vd[j].w += fabsf(rr[j + 1].w - rr[j].w);
        }
#pragma unroll
        for (int k = 0; k < 4; ++k) {
            float4 R = rr[k + 1];
            float sr = F[(size_t)ry[k + 1] * WW + cxr];
            float sl = F[(size_t)ry[k + 1] * WW + cxl];
            hd[k].x += fabsf(R.y - R.x);
            hd[k].y += fabsf(R.z - R.y);
            hd[k].z += fabsf(R.w - R.z);
            hd[k].w += fabsf(sr - R.w);
            hmd[k] += fabsf(R.x - sl);
            if (c == 3) { imv[k] = R; slv[k] = sl; srv[k] = sr; }
        }
        if (c == 3) { r0v = rr[0]; r5v = rr[5]; }
    }
    float4 cvR[5], chR[4];
    float hmR[4];
#pragma unroll
    for (int j = 0; j < 5; ++j) {
        int y = gy - 1 + j;
        if (y < 0 || y > 1022) {
            cvR[j] = z4;
        } else {
            cvR[j] = make_float4(gfun(vd[j].x * 0.25f), gfun(vd[j].y * 0.25f),
                                 gfun(vd[j].z * 0.25f), gfun(vd[j].w * 0.25f));
        }
    }
#pragma unroll
    for (int k = 0; k < 4; ++k) {
        chR[k] = make_float4(gfun(hd[k].x * 0.25f), gfun(hd[k].y * 0.25f),
                             gfun(hd[k].z * 0.25f), gfun(hd[k].w * 0.25f));
        if (gx + 3 == 1023) chR[k].w = 0.f;
        hmR[k] = (gx > 0) ? gfun(hmd[k] * 0.25f) : 0.f;
    }
    // cv/ch output slices for this tile
#pragma unroll
    for (int j = 1; j < 5; ++j) {
        int y = gy + j - 1;
        if (y <= 1022)
            *(float4*)(out_cv + (size_t)b * CVN + (size_t)y * WW + gx) = cvR[j];
    }
#pragma unroll
    for (int k = 0; k < 4; ++k) {
        float* base = out_ch + (size_t)b * CVN + (size_t)(gy + k) * 1023;
        base[gx + 0] = chR[k].x;
        base[gx + 1] = chR[k].y;
        base[gx + 2] = chR[k].z;
        if (gx + 3 < 1023) base[gx + 3] = chR[k].w;
    }

    // 8x8 cell: rows = cyL pair (cyL>>1), cols = lane pair (g>>1)
    int sidx = b * SHW + (tileY * 8 + (cyL >> 1)) * 128 + tileX * 16 + (g >> 1);
    float sval = src[sidx] + shift;
    bool masked = mask[sidx] < 0.5f;

    bool upAct = (cyL == 0  && tileY > 0);
    bool dnAct = (cyL == 15 && tileY < 15);
    bool lAct  = (g == 0  && tileX > 0);
    bool rAct  = (g == 31 && tileX < 7);
    bool pubTop = (wv == 0 && tileY > 0);
    bool pubBot = (wv == 7 && tileY < 15);

    // interior state in registers; init img0 = yb + shift
    float4 cur[4];
#pragma unroll
    for (int k = 0; k < 4; ++k) {
        float4 v = imv[k];
        v.x += shift; v.y += shift; v.z += shift; v.w += shift;
        cur[k] = v;
    }
    float4 hUp = z4, hDn = z4;
    float xlR[4] = {0.f, 0.f, 0.f, 0.f}, xrR[4] = {0.f, 0.f, 0.f, 0.f};
    if (upAct) { hUp = r0v; hUp.x += shift; hUp.y += shift; hUp.z += shift; hUp.w += shift; }
    if (dnAct) { hDn = r5v; hDn.x += shift; hDn.y += shift; hDn.z += shift; hDn.w += shift; }
    if (lAct) {
#pragma unroll
        for (int k = 0; k < 4; ++k) xlR[k] = slv[k] + shift;
    }
    if (rAct) {
#pragma unroll
        for (int k = 0; k < 4; ++k) xrR[k] = srv[k] + shift;
    }
    // seed boundary LDS slot 0 with state-0 top/bot rows of each cyL group
    *(float4*)&bnd[0][cyL][0][lx0] = cur[0];
    *(float4*)&bnd[0][cyL][1][lx0] = cur[3];
    __syncthreads();

    for (int t = 0; t < NPRE; ++t) {
        int par = t & 1;
        // ---- 1: issue poll loads for state-t halos (tag=t, parity=t&1) ----
        unsigned sP = (unsigned)t;
        size_t rOffP = par ? ROWPAR : 0;
        size_t cOffP = par ? COLPAR : 0;
        const u64* pUp = upAct ? &bufRow[rOffP + (((size_t)blk - 8) * 2 + 1) * 128 + lx0] : nullptr;
        const u64* pDn = dnAct ? &bufRow[rOffP + (((size_t)blk + 8) * 2 + 0) * 128 + lx0] : nullptr;
        const u64* pL  = lAct  ? &bufCol[cOffP + (((size_t)blk - 1) * 2 + 1) * 64 + ly0] : nullptr;
        const u64* pR  = rAct  ? &bufCol[cOffP + (((size_t)blk + 1) * 2 + 0) * 64 + ly0] : nullptr;
        uint4v uA, uB, dA, dB, lA, lB, rA, rB;
        bool pollRound = (t > 0);    // t==0 halos live in registers from init
        if (pollRound) {
            if (upAct) { uA = uld4(pUp); uB = uld4(pUp + 2); }
            if (dnAct) { dA = uld4(pDn); dB = uld4(pDn + 2); }
            if (lAct)  { lA = uld4(pL);  lB = uld4(pL + 2); }
            if (rAct)  { rA = uld4(pR);  rB = uld4(pR + 2); }
        }

        // ---- 2: intra-tile boundary rows of state t from LDS slot par ----
        float4 ldsUp = z4, ldsDn = z4;
        if (cyL > 0)  ldsUp = *(float4*)&bnd[par][cyL - 1][1][lx0];
        if (cyL < 15) ldsDn = *(float4*)&bnd[par][cyL + 1][0][lx0];

        // ---- 3: BASE stencil in registers (halo terms = 0), in-place ----
        float4 pu = (cyL == 0) ? z4 : ldsUp;
        float4 pc = cur[0];
        float csum = 0.f;
#pragma unroll
        for (int k = 0; k < 4; ++k) {
            float4 dn = (k == 3) ? ((cyL == 15) ? z4 : ldsDn) : cur[k + 1];
            float4 cu = cvR[k], cd = cvR[k + 1], h4 = chR[k];
            float xs = __shfl_up(pc.w, 1);
            float xt = __shfl_down(pc.x, 1);
            float xl = (g == 0)  ? 0.f : xs;
            float xr = (g == 31) ? 0.f : xt;
            float hm = hmR[k];
            float4 a;
            a.x = pc.x + LL * (cd.x * (dn.x - pc.x) - cu.x * (pc.x - pu.x)
                             + h4.x * (pc.y - pc.x) - hm   * (pc.x - xl));
            a.y = pc.y + LL * (cd.y * (dn.y - pc.y) - cu.y * (pc.y - pu.y)
                             + h4.y * (pc.z - pc.y) - h4.x * (pc.y - pc.x));
            a.z = pc.z + LL * (cd.z * (dn.z - pc.z) - cu.z * (pc.z - pu.z)
                             + h4.z * (pc.w - pc.z) - h4.y * (pc.z - pc.y));
            a.w = pc.w + LL * (cd.w * (dn.w - pc.w) - cu.w * (pc.w - pu.w)
                             + h4.w * (xr   - pc.w) - h4.z * (pc.w - pc.z));
            csum += a.x + a.y + a.z + a.w;
            cur[k] = a;
            pu = pc; pc = dn;
        }

        // ---- 4: resolve halos (loads had the whole base compute to land) ----
        if (pollRound) {
            vwait();
            bool needU = upAct, needD = dnAct, needL = lAct, needR = rAct;
            for (;;) {
                if (needU && tags_ok(uA, uB, sP)) { hUp = vals_of(uA, uB); needU = false; }
                if (needD && tags_ok(dA, dB, sP)) { hDn = vals_of(dA, dB); needD = false; }
                if (needL && tags_ok(lA, lB, sP)) {
                    float4 c = vals_of(lA, lB);
                    xlR[0] = c.x; xlR[1] = c.y; xlR[2] = c.z; xlR[3] = c.w;
                    needL = false;
                }
                if (needR && tags_ok(rA, rB, sP)) {
                    float4 c = vals_of(rA, rB);
                    xrR[0] = c.x; xrR[1] = c.y; xrR[2] = c.z; xrR[3] = c.w;
                    needR = false;
                }
                if (__all(!(needU || needD || needL || needR))) break;
                __builtin_amdgcn_s_sleep(1);
                if (needU) { uA = uld4(pUp); uB = uld4(pUp + 2); }
                if (needD) { dA = uld4(pDn); dB = uld4(pDn + 2); }
                if (needL) { lA = uld4(pL);  lB = uld4(pL + 2); }
                if (needR) { rA = uld4(pR);  rB = uld4(pR + 2); }
                vwait();
            }
        }

        // ---- 5: linear corrections (zero-conductance borders self-mask) ----
        float cadd = 0.f;
        if (cyL == 0) {
            float4 cu = cvR[0];
            float c0 = LL * cu.x * hUp.x, c1 = LL * cu.y * hUp.y;
            float c2 = LL * cu.z * hUp.z, c3 = LL * cu.w * hUp.w;
            cur[0].x += c0; cur[0].y += c1; cur[0].z += c2; cur[0].w += c3;
            cadd += c0 + c1 + c2 + c3;
        }
        if (cyL == 15) {
            float4 cd = cvR[4];
            float c0 = LL * cd.x * hDn.x, c1 = LL * cd.y * hDn.y;
            float c2 = LL * cd.z * hDn.z, c3 = LL * cd.w * hDn.w;
            cur[3].x += c0; cur[3].y += c1; cur[3].z += c2; cur[3].w += c3;
            cadd += c0 + c1 + c2 + c3;
        }
        if (g == 0) {
#pragma unroll
            for (int k = 0; k < 4; ++k) {
                float c = LL * hmR[k] * xlR[k];
                cur[k].x += c; cadd += c;
            }
        }
        if (g == 31) {
#pragma unroll
            for (int k = 0; k < 4; ++k) {
                float c = LL * chR[k].w * xrR[k];
                cur[k].w += c; cadd += c;
            }
        }
        csum += cadd;
        csum += __shfl_xor(csum, 1);
        csum += __shfl_xor(csum, 32);   // cell lanes {tid, tid^1, tid^32, tid^33}
        float ratio = masked ? 1.0f : sval / (csum * (1.0f / 64.0f) + EPSF);

        if (t == NPRE - 1) {
            float* ob = out + (size_t)b * NPIX;
#pragma unroll
            for (int k = 0; k < 4; ++k) {
                float4 v = cur[k];
                v.x = v.x * ratio - shift; v.y = v.y * ratio - shift;
                v.z = v.z * ratio - shift; v.w = v.w * ratio - shift;
                *(float4*)(ob + (size_t)(gy + k) * WW + gx) = v;
            }
            break;
        }
#pragma unroll
        for (int k = 0; k < 4; ++k) {
            cur[k].x *= ratio; cur[k].y *= ratio; cur[k].z *= ratio; cur[k].w *= ratio;
        }

        // ---- 6: publish edges tagged s2 = t+1 ----
        unsigned s2 = (unsigned)(t + 1);
        size_t rOff2 = (s2 & 1) ? ROWPAR : 0;
        size_t cOff2 = (s2 & 1) ? COLPAR : 0;
        if (pubTop) {   // wave 0: top row lives in cur[0] of lanes 0..31 (cyL0)
            float a = __shfl(cur[0].x, l0 >> 1), bq = __shfl(cur[0].y, l0 >> 1);
            float c = __shfl(cur[0].z, l0 >> 1), d = __shfl(cur[0].w, l0 >> 1);
            float v0 = (l0 & 1) ? c : a, v1 = (l0 & 1) ? d : bq;
            uint4v q; q.x = __float_as_uint(v0); q.y = s2;
            q.z = __float_as_uint(v1); q.w = s2;
            ust4(&bufRow[rOff2 + ((size_t)blk * 2 + 0) * 128 + 2 * l0], q);
        }
        if (pubBot) {   // wave 7: bottom row in cur[3] of local lanes 32..63 (cyL15)
            int sl = 32 + (l0 >> 1);
            float a = __shfl(cur[3].x, sl), bq = __shfl(cur[3].y, sl);
            float c = __shfl(cur[3].z, sl), d = __shfl(cur[3].w, sl);
            float v0 = (l0 & 1) ? c : a, v1 = (l0 & 1) ? d : bq;
            uint4v q; q.x = __float_as_uint(v0); q.y = s2;
            q.z = __float_as_uint(v1); q.w = s2;
            ust4(&bufRow[rOff2 + ((size_t)blk * 2 + 1) * 128 + 2 * l0], q);
        }
        if (lAct) {     // 16 edge threads x 4 rows = 64 u64 per line
            u64* p = &bufCol[cOff2 + ((size_t)blk * 2 + 0) * 64 + ly0];
            pub2(p,     cur[0].x, cur[1].x, s2);
            pub2(p + 2, cur[2].x, cur[3].x, s2);
        }
        if (rAct) {
            u64* p = &bufCol[cOff2 + ((size_t)blk * 2 + 1) * 64 + ly0];
            pub2(p,     cur[0].w, cur[1].w, s2);
            pub2(p + 2, cur[2].w, cur[3].w, s2);
        }

        // ---- 7: boundary rows of state t+1 into LDS slot par^1; barrier ----
        *(float4*)&bnd[par ^ 1][cyL][0][lx0] = cur[0];
        *(float4*)&bnd[par ^ 1][cyL][1][lx0] = cur[3];
        BAR();   // publish stores cross in flight; LDS visible
    }
}

extern "C" void kernel_launch(void* const* d_in, const int* in_sizes, int n_in,
                              void* d_out, int out_size, void* d_ws, size_t ws_size,
                              hipStream_t stream) {
    const float* guide = (const float*)d_in[0];   // [2,3,1024,1024]
    const float* yb    = (const float*)d_in[1];   // [2,1,1024,1024]
    const float* src   = (const float*)d_in[2];   // [2,1,128,128]
    const float* mask  = (const float*)d_in[3];   // [2,1,128,128]

    float* out    = (float*)d_out;                       // y_pred [2,1,1024,1024]
    float* out_cv = out + (size_t)BB * NPIX;             // cv [2,1,1023,1024]
    float* out_ch = out_cv + (size_t)BB * CVN;           // ch [2,1,1024,1023]

    // ws: halo exchange buffers only. 0xAA poison can't match tags in [1,64).
    u64* bufRow = (u64*)d_ws;                            // 2 par x 256 x 2 x 128
    u64* bufCol = bufRow + 2 * ROWPAR;                   // 2 par x 256 x 2 x 64

    persist_kernel<<<NB, TPB, 0, stream>>>(guide, yb, src, mask, out, out_cv,
                                           out_ch, bufRow, bufCol);
}